// Round 9
// baseline (303.767 us; speedup 1.0000x reference)
//
#include <hip/hip_runtime.h>
#include <hip/hip_bf16.h>

#define N_Q   16384
#define MCTX  4096
#define DSIN  256
#define YDIM  7
#define PDIM  256   // SPROJ
#define BK    32

typedef __attribute__((ext_vector_type(8))) short s16x8;   // 8 bf16 (4 VGPRs)
typedef __attribute__((ext_vector_type(4))) float f32x4;   // MFMA C/D frag
typedef unsigned short u16;

static __device__ __forceinline__ u16 f2bf(float f) {
    union { float f; unsigned u; } v; v.f = f;
    unsigned r = v.u + 0x7fffu + ((v.u >> 16) & 1u);  // RNE
    return (u16)(r >> 16);
}
static __device__ __forceinline__ float bf2f(u16 h) {
    union { unsigned u; float f; } v; v.u = ((unsigned)h) << 16;
    return v.f;
}
static __device__ __forceinline__ f32x4 mfma16(s16x8 a, s16x8 b, f32x4 c) {
    return __builtin_amdgcn_mfma_f32_16x16x32_bf16(a, b, c, 0, 0, 0);
}

// ---------------- K_prep: (a) Wq transpose + hi/lo split, (b) YKb (frag layout) + YVb ----
// YKb layout (u16 units): chunk ci = (kb*8 + kf)*2 + keyhalf, 512 u16 per chunk;
// lane l's 16B at [ci*512 + l*8] = K[kb*32 + keyhalf*16 + (l&15)][kf*32 + (l>>4)*8 .. +8]
// (scaled 1/16). This is exactly the 16x16x32 MFMA B-frag for QK, so k_attn reads it
// as one coalesced 1KB global load per frag — K never touches LDS.
__global__ void k_prep(const float* __restrict__ Wq, u16* __restrict__ WtH,
                       u16* __restrict__ WtL, const float* __restrict__ y,
                       const float* __restrict__ Wk, const float* __restrict__ Wv,
                       u16* __restrict__ YKb, u16* __restrict__ YVb) {
    if (blockIdx.x < PDIM) {
        int n = blockIdx.x;   // 0..PDIM-1
        int k = threadIdx.x;  // 0..DSIN-1
        float w = Wq[(size_t)k * PDIM + n];
        u16 h = f2bf(w);
        WtH[(size_t)n * DSIN + k] = h;
        WtL[(size_t)n * DSIN + k] = f2bf(w - bf2f(h));
    } else {
        int kb = blockIdx.x - PDIM;  // key block (32 keys)
        int p  = threadIdx.x;        // proj dim (d for K, p for V)
        float wk[YDIM], wv[YDIM];
#pragma unroll
        for (int j = 0; j < YDIM; ++j) {
            wk[j] = Wk[(size_t)j * PDIM + p];
            wv[j] = Wv[(size_t)j * PDIM + p];
        }
        u16 vbuf[32], akb[32];
#pragma unroll
        for (int m = 0; m < 32; ++m) {
            int key = kb * 32 + m;
            float ak = 0.f, av = 0.f;
#pragma unroll
            for (int j = 0; j < YDIM; ++j) {
                float yy = y[(size_t)key * YDIM + j];
                ak += yy * wk[j];
                av += yy * wv[j];
            }
            akb[m] = f2bf(ak * 0.0625f);  // fold 1/sqrt(256)
            vbuf[m] = f2bf(av);
        }
        // YVb: coalesced PV-frag layout [kb][p][32] (64B contiguous per thread)
        s16x8* dst = (s16x8*)(YVb + ((size_t)kb * PDIM + p) * 32);
#pragma unroll
        for (int c = 0; c < 4; ++c) dst[c] = ((s16x8*)vbuf)[c];
        // YKb: frag layout; thread p owns d=p -> (kf, quad-pos, byte j) fixed, key -> lane
        int kf = p >> 5;
        int qp = (p >> 3) & 3;
        int jj = p & 7;
        size_t base = ((size_t)kb * 8 + kf) * 1024;  // 2 keyhalf chunks of 512 u16
#pragma unroll
        for (int m = 0; m < 32; ++m) {
            int kh = m >> 4;
            int l  = qp * 16 + (m & 15);
            YKb[base + (size_t)kh * 512 + l * 8 + jj] = akb[m];
        }
    }
}

// ---------------- K1: XQ = x @ Wq, hi/lo split; 32-row tiles, 2 blocks/CU ----------------
__global__ __launch_bounds__(256, 2) void k_xq(const float* __restrict__ x,
                                               const u16* __restrict__ WtH,
                                               const u16* __restrict__ WtL,
                                               u16* __restrict__ XQ) {
    __shared__ u16 xH[32 * 256];  // XOR-swizzled 16B chunks: phys c = c ^ (row&7)
    __shared__ u16 xL[32 * 256];
    const int tid = threadIdx.x;
    const int rowg0 = blockIdx.x * 32;
#pragma unroll
    for (int i = 0; i < 4; ++i) {
        int row = (tid >> 5) + i * 8;
        int c32 = tid & 31;
        const float* px = x + (size_t)(rowg0 + row) * DSIN + c32 * 8;
        float4 a = *(const float4*)px;
        float4 b = *(const float4*)(px + 4);
        float vals[8] = {a.x, a.y, a.z, a.w, b.x, b.y, b.z, b.w};
        s16x8 h, l;
#pragma unroll
        for (int j = 0; j < 8; ++j) {
            u16 hh = f2bf(vals[j]);
            h[j] = (short)hh;
            l[j] = (short)f2bf(vals[j] - bf2f(hh));
        }
        int pc = c32 ^ (row & 7);
        *(s16x8*)(xH + row * 256 + pc * 8) = h;
        *(s16x8*)(xL + row * 256 + pc * 8) = l;
    }
    __syncthreads();

    const int wave = tid >> 6, lane = tid & 63;
    const int quad = lane >> 4, m16 = lane & 15;
    const int rh = wave & 1, ph = wave >> 1;
    const int rowl = rh * 16 + m16;
    const int swz = rowl & 7;
    s16x8 ah[8], al[8];
#pragma unroll
    for (int kf = 0; kf < 8; ++kf) {
        int pc = (kf * 4 + quad) ^ swz;
        ah[kf] = *(const s16x8*)(xH + rowl * 256 + pc * 8);
        al[kf] = *(const s16x8*)(xL + rowl * 256 + pc * 8);
    }
#pragma unroll
    for (int ptl = 0; ptl < 8; ++ptl) {
        int pt = ph * 8 + ptl;
        f32x4 acc = (f32x4){0.f, 0.f, 0.f, 0.f};
#pragma unroll
        for (int kf = 0; kf < 8; ++kf) {
            size_t idx = (size_t)(pt * 16 + m16) * DSIN + kf * 32 + quad * 8;
            s16x8 bh = *(const s16x8*)(WtH + idx);
            s16x8 bl = *(const s16x8*)(WtL + idx);
            acc = mfma16(ah[kf], bh, acc);
            acc = mfma16(al[kf], bh, acc);
            acc = mfma16(ah[kf], bl, acc);
        }
#pragma unroll
        for (int r = 0; r < 4; ++r)
            XQ[(size_t)(rowg0 + rh * 16 + quad * 4 + r) * PDIM + pt * 16 + m16] =
                f2bf(acc[r]);
    }
}

// ---------------- K3: fused attention — R8 structure, K-frags from GLOBAL (no Kt) ----
// Block: 64 q x 256 p, 4 waves. Wave w: S-quarter (rows w*16..+16) via QK with B-frags
// read directly from L2-resident YKb (coalesced 1KB/frag); exp/relu -> bf16 Pe/Pr LDS;
// PV over p-slice [64w,64w+64). LDS holds ONLY Pe/Pr (10KB) — K LDS reads, K-DMA and
// their bank conflicts are gone; LDS pipe (was ~85% busy) keeps only P traffic.
__global__ __launch_bounds__(256, 2) void k_attn(const u16* __restrict__ XQ,
                                                 const u16* __restrict__ YKb,
                                                 const u16* __restrict__ YVb,
                                                 u16* __restrict__ accE,
                                                 u16* __restrict__ accR,
                                                 float* __restrict__ lsum,
                                                 float* __restrict__ rsum,
                                                 int msPerSplit) {
    __shared__ u16 Pe[64 * 40];    // 64 q x 32 keys, pad->40 (2-way max)
    __shared__ u16 Pr[64 * 40];

    const int tid = threadIdx.x;
    const int wave = tid >> 6, lane = tid & 63;
    const int quad = lane >> 4, m16 = lane & 15;
    const int split = blockIdx.y;
    const int qbase = blockIdx.x * 64;
    const int key_begin = split * msPerSplit;
    const int iters = msPerSplit / BK;
    const int pslice = wave * 64;

    // Q A-frags for this wave's 16 S-rows
    s16x8 qf[8];
    const u16* qp = XQ + (size_t)(qbase + wave * 16 + m16) * DSIN;
#pragma unroll
    for (int kf = 0; kf < 8; ++kf)
        qf[kf] = *(const s16x8*)(qp + kf * 32 + quad * 8);

    f32x4 aE[4][4], aR[4][4];
#pragma unroll
    for (int g = 0; g < 4; ++g)
#pragma unroll
        for (int t = 0; t < 4; ++t) {
            aE[g][t] = (f32x4){0.f, 0.f, 0.f, 0.f};
            aR[g][t] = (f32x4){0.f, 0.f, 0.f, 0.f};
        }
    float lacc[4] = {0.f, 0.f, 0.f, 0.f}, racc[4] = {0.f, 0.f, 0.f, 0.f};

    for (int it = 0; it < iters; ++it) {
        const int key0 = key_begin + it * BK;
        __syncthreads();   // PV(it-1) reads done; Pe/Pr free for this iter's writes

        // QK: B-frags straight from global YKb (coalesced; L1/L2-resident)
        const u16* kbase = YKb + (size_t)(key0 >> 5) * 8192;
        f32x4 s0 = (f32x4){0.f, 0.f, 0.f, 0.f};
        f32x4 s1 = (f32x4){0.f, 0.f, 0.f, 0.f};
        __builtin_amdgcn_s_setprio(1);
#pragma unroll
        for (int kf = 0; kf < 8; ++kf) {
            s16x8 b0 = *(const s16x8*)(kbase + (size_t)(kf * 2 + 0) * 512 + lane * 8);
            s16x8 b1 = *(const s16x8*)(kbase + (size_t)(kf * 2 + 1) * 512 + lane * 8);
            s0 = mfma16(qf[kf], b0, s0);
            s1 = mfma16(qf[kf], b1, s1);
        }
        __builtin_amdgcn_s_setprio(0);
        // exp/relu in C-layout; per-lane partial row sums; bf16 -> Pe/Pr
#pragma unroll
        for (int r = 0; r < 4; ++r) {
            float e0 = __expf(s0[r]), e1 = __expf(s1[r]);
            float rl0 = fmaxf(s0[r], 0.f), rl1 = fmaxf(s1[r], 0.f);
            lacc[r] += e0 + e1;
            racc[r] += rl0 + rl1;
            int row = wave * 16 + quad * 4 + r;
            Pe[row * 40 + m16]      = f2bf(e0);
            Pe[row * 40 + 16 + m16] = f2bf(e1);
            Pr[row * 40 + m16]      = f2bf(rl0);
            Pr[row * 40 + 16 + m16] = f2bf(rl1);
        }
        __syncthreads();   // Pe/Pr visible

        // V-frags from global, then PV (dual path, V-frag reused 8x)
        s16x8 vf[4];
        const u16* vb = YVb + (size_t)((key0 >> 5) * PDIM) * 32;
#pragma unroll
        for (int t = 0; t < 4; ++t)
            vf[t] = *(const s16x8*)(vb + (size_t)(pslice + t * 16 + m16) * 32 + quad * 8);

        __builtin_amdgcn_s_setprio(1);
#pragma unroll
        for (int g = 0; g < 4; ++g) {
            s16x8 pa = *(const s16x8*)(Pe + (g * 16 + m16) * 40 + quad * 8);
            s16x8 pb = *(const s16x8*)(Pr + (g * 16 + m16) * 40 + quad * 8);
#pragma unroll
            for (int t = 0; t < 4; ++t) {
                aE[g][t] = mfma16(pa, vf[t], aE[g][t]);
                aR[g][t] = mfma16(pb, vf[t], aR[g][t]);
            }
        }
        __builtin_amdgcn_s_setprio(0);
    }

    // epilogue: bf16 partial O and row sums
    size_t ob = ((size_t)split * N_Q + qbase) * PDIM;
#pragma unroll
    for (int g = 0; g < 4; ++g)
#pragma unroll
        for (int t = 0; t < 4; ++t)
#pragma unroll
            for (int r = 0; r < 4; ++r) {
                size_t o = ob + (size_t)(g * 16 + quad * 4 + r) * PDIM + pslice + t * 16 + m16;
                accE[o] = f2bf(aE[g][t][r]);
                accR[o] = f2bf(aR[g][t][r]);
            }
#pragma unroll
    for (int r = 0; r < 4; ++r) {
        lacc[r] += __shfl_xor(lacc[r], 1);
        lacc[r] += __shfl_xor(lacc[r], 2);
        lacc[r] += __shfl_xor(lacc[r], 4);
        lacc[r] += __shfl_xor(lacc[r], 8);
        racc[r] += __shfl_xor(racc[r], 1);
        racc[r] += __shfl_xor(racc[r], 2);
        racc[r] += __shfl_xor(racc[r], 4);
        racc[r] += __shfl_xor(racc[r], 8);
    }
    if (m16 < 4) {
        float lv = (m16 == 0) ? lacc[0] : (m16 == 1) ? lacc[1] : (m16 == 2) ? lacc[2] : lacc[3];
        float rv = (m16 == 0) ? racc[0] : (m16 == 1) ? racc[1] : (m16 == 2) ? racc[2] : racc[3];
        int row = split * N_Q + qbase + wave * 16 + quad * 4 + m16;
        lsum[row] = lv;
        rsum[row] = rv;
    }
}

// ---------------- K4: combine splits + normalization (bf16 partials in) ----------------
__global__ void k_comb(const u16* __restrict__ accE, const u16* __restrict__ accR,
                       const float* __restrict__ lsum, const float* __restrict__ rsum,
                       float* __restrict__ out, int nsplit) {
    int row = blockIdx.x * 8 + (threadIdx.x >> 5);
    int col = (threadIdx.x & 31) * 8;
    size_t idx = (size_t)row * PDIM + col;
    const size_t NP = (size_t)N_Q * PDIM;
    float E[8] = {0.f, 0.f, 0.f, 0.f, 0.f, 0.f, 0.f, 0.f};
    float R[8] = {0.f, 0.f, 0.f, 0.f, 0.f, 0.f, 0.f, 0.f};
    float L = 0.f, Rs = 0.f;
    for (int s = 0; s < nsplit; ++s) {
        s16x8 e = *(const s16x8*)(accE + s * NP + idx);
        s16x8 r = *(const s16x8*)(accR + s * NP + idx);
#pragma unroll
        for (int j = 0; j < 8; ++j) {
            E[j] += bf2f((u16)e[j]);
            R[j] += bf2f((u16)r[j]);
        }
        L  += lsum[(size_t)s * N_Q + row];
        Rs += rsum[(size_t)s * N_Q + row];
    }
    float invL = 1.f / L, invD = 1.f / (1.f + 0.1f * Rs);
    float4 o0, o1;
    o0.x = (0.1f * R[0] + E[0] * invL) * invD;
    o0.y = (0.1f * R[1] + E[1] * invL) * invD;
    o0.z = (0.1f * R[2] + E[2] * invL) * invD;
    o0.w = (0.1f * R[3] + E[3] * invL) * invD;
    o1.x = (0.1f * R[4] + E[4] * invL) * invD;
    o1.y = (0.1f * R[5] + E[5] * invL) * invD;
    o1.z = (0.1f * R[6] + E[6] * invL) * invD;
    o1.w = (0.1f * R[7] + E[7] * invL) * invD;
    *(float4*)(out + idx) = o0;
    *(float4*)(out + idx + 4) = o1;
}

extern "C" void kernel_launch(void* const* d_in, const int* in_sizes, int n_in,
                              void* d_out, int out_size, void* d_ws, size_t ws_size,
                              hipStream_t stream) {
    const float* x  = (const float*)d_in[0];
    const float* y  = (const float*)d_in[1];
    const float* Wq = (const float*)d_in[2];
    const float* Wk = (const float*)d_in[3];
    const float* Wv = (const float*)d_in[4];
    float* out = (float*)d_out;

    char* ws = (char*)d_ws;
    size_t off = 0;
    auto take = [&](size_t bytes) -> char* {
        char* p = ws + off;
        off += (bytes + 255) & ~(size_t)255;
        return p;
    };
    u16* XQ  = (u16*)take((size_t)N_Q * PDIM * 2);
    u16* WtH = (u16*)take((size_t)PDIM * DSIN * 2);
    u16* WtL = (u16*)take((size_t)PDIM * DSIN * 2);
    u16* YKb = (u16*)take((size_t)MCTX * PDIM * 2);
    u16* YVb = (u16*)take((size_t)MCTX * PDIM * 2);

    size_t perSplit = (size_t)N_Q * PDIM * 2 * 2 + (size_t)N_Q * 4 * 2 + 1024;
    int nsplit = (ws_size >= off + 2 * perSplit + 4096) ? 2 : 1;

    u16*   accE = (u16*)take((size_t)nsplit * N_Q * PDIM * 2);
    u16*   accR = (u16*)take((size_t)nsplit * N_Q * PDIM * 2);
    float* lsum = (float*)take((size_t)nsplit * N_Q * 4);
    float* rsum = (float*)take((size_t)nsplit * N_Q * 4);

    hipLaunchKernelGGL(k_prep, dim3(PDIM + MCTX/32), dim3(256), 0, stream,
                       Wq, WtH, WtL, y, Wk, Wv, YKb, YVb);
    hipLaunchKernelGGL(k_xq,   dim3(N_Q/32), dim3(256), 0, stream, x, WtH, WtL, XQ);
    hipLaunchKernelGGL(k_attn, dim3(N_Q/64, nsplit), dim3(256), 0, stream,
                       XQ, YKb, YVb, accE, accR, lsum, rsum, MCTX / nsplit);
    hipLaunchKernelGGL(k_comb, dim3(N_Q/8), dim3(256), 0, stream,
                       accE, accR, lsum, rsum, out, nsplit);
}

// Round 10
// 297.546 us; speedup vs baseline: 1.0209x; 1.0209x over previous
//
#include <hip/hip_runtime.h>
#include <hip/hip_bf16.h>

#define N_Q   16384
#define MCTX  4096
#define DSIN  256
#define YDIM  7
#define PDIM  256   // SPROJ
#define BK    32

typedef __attribute__((ext_vector_type(8))) short s16x8;   // 8 bf16 (4 VGPRs)
typedef __attribute__((ext_vector_type(4))) float f32x4;   // MFMA C/D frag
typedef unsigned short u16;

static __device__ __forceinline__ u16 f2bf(float f) {
    union { float f; unsigned u; } v; v.f = f;
    unsigned r = v.u + 0x7fffu + ((v.u >> 16) & 1u);  // RNE
    return (u16)(r >> 16);
}
static __device__ __forceinline__ float bf2f(u16 h) {
    union { unsigned u; float f; } v; v.u = ((unsigned)h) << 16;
    return v.f;
}
static __device__ __forceinline__ f32x4 mfma16(s16x8 a, s16x8 b, f32x4 c) {
    return __builtin_amdgcn_mfma_f32_16x16x32_bf16(a, b, c, 0, 0, 0);
}
// async 16B global->LDS DMA (dst = wave-uniform base + lane*16)
static __device__ __forceinline__ void gload_lds16(const u16* g, u16* l) {
    __builtin_amdgcn_global_load_lds(
        (const __attribute__((address_space(1))) unsigned int*)(g),
        (__attribute__((address_space(3))) unsigned int*)(l), 16, 0, 0);
}

// ---------------- K_prep: (a) Wq transpose + hi/lo split, (b) YK + YVb ----------------
__global__ void k_prep(const float* __restrict__ Wq, u16* __restrict__ WtH,
                       u16* __restrict__ WtL, const float* __restrict__ y,
                       const float* __restrict__ Wk, const float* __restrict__ Wv,
                       u16* __restrict__ YK, u16* __restrict__ YVb) {
    if (blockIdx.x < PDIM) {
        int n = blockIdx.x;   // 0..PDIM-1
        int k = threadIdx.x;  // 0..DSIN-1
        float w = Wq[(size_t)k * PDIM + n];
        u16 h = f2bf(w);
        WtH[(size_t)n * DSIN + k] = h;
        WtL[(size_t)n * DSIN + k] = f2bf(w - bf2f(h));
    } else {
        // YK scaled 1/16 row-major [key][p]; YVb coalesced PV-frag layout [kb][p][32]
        int kb = blockIdx.x - PDIM;  // key block (32 keys)
        int p  = threadIdx.x;        // proj
        float wk[YDIM], wv[YDIM];
#pragma unroll
        for (int j = 0; j < YDIM; ++j) {
            wk[j] = Wk[(size_t)j * PDIM + p];
            wv[j] = Wv[(size_t)j * PDIM + p];
        }
        u16 vbuf[32];
#pragma unroll
        for (int m = 0; m < 32; ++m) {
            int key = kb * 32 + m;
            float ak = 0.f, av = 0.f;
#pragma unroll
            for (int j = 0; j < YDIM; ++j) {
                float yy = y[(size_t)key * YDIM + j];
                ak += yy * wk[j];
                av += yy * wv[j];
            }
            YK[(size_t)key * PDIM + p] = f2bf(ak * 0.0625f);  // fold 1/sqrt(256)
            vbuf[m] = f2bf(av);
        }
        s16x8* dst = (s16x8*)(YVb + ((size_t)kb * PDIM + p) * 32);
#pragma unroll
        for (int c = 0; c < 4; ++c) dst[c] = ((s16x8*)vbuf)[c];
    }
}

// ---------------- K1: XQ = x @ Wq, hi/lo split; 32-row tiles, 2 blocks/CU ----------------
__global__ __launch_bounds__(256, 2) void k_xq(const float* __restrict__ x,
                                               const u16* __restrict__ WtH,
                                               const u16* __restrict__ WtL,
                                               u16* __restrict__ XQ) {
    __shared__ u16 xH[32 * 256];  // XOR-swizzled 16B chunks: phys c = c ^ (row&7)
    __shared__ u16 xL[32 * 256];
    const int tid = threadIdx.x;
    const int rowg0 = blockIdx.x * 32;
#pragma unroll
    for (int i = 0; i < 4; ++i) {
        int row = (tid >> 5) + i * 8;
        int c32 = tid & 31;
        const float* px = x + (size_t)(rowg0 + row) * DSIN + c32 * 8;
        float4 a = *(const float4*)px;
        float4 b = *(const float4*)(px + 4);
        float vals[8] = {a.x, a.y, a.z, a.w, b.x, b.y, b.z, b.w};
        s16x8 h, l;
#pragma unroll
        for (int j = 0; j < 8; ++j) {
            u16 hh = f2bf(vals[j]);
            h[j] = (short)hh;
            l[j] = (short)f2bf(vals[j] - bf2f(hh));
        }
        int pc = c32 ^ (row & 7);
        *(s16x8*)(xH + row * 256 + pc * 8) = h;
        *(s16x8*)(xL + row * 256 + pc * 8) = l;
    }
    __syncthreads();

    const int wave = tid >> 6, lane = tid & 63;
    const int quad = lane >> 4, m16 = lane & 15;
    const int rh = wave & 1, ph = wave >> 1;
    const int rowl = rh * 16 + m16;
    const int swz = rowl & 7;
    s16x8 ah[8], al[8];
#pragma unroll
    for (int kf = 0; kf < 8; ++kf) {
        int pc = (kf * 4 + quad) ^ swz;
        ah[kf] = *(const s16x8*)(xH + rowl * 256 + pc * 8);
        al[kf] = *(const s16x8*)(xL + rowl * 256 + pc * 8);
    }
#pragma unroll
    for (int ptl = 0; ptl < 8; ++ptl) {
        int pt = ph * 8 + ptl;
        f32x4 acc = (f32x4){0.f, 0.f, 0.f, 0.f};
#pragma unroll
        for (int kf = 0; kf < 8; ++kf) {
            size_t idx = (size_t)(pt * 16 + m16) * DSIN + kf * 32 + quad * 8;
            s16x8 bh = *(const s16x8*)(WtH + idx);
            s16x8 bl = *(const s16x8*)(WtL + idx);
            acc = mfma16(ah[kf], bh, acc);
            acc = mfma16(al[kf], bh, acc);
            acc = mfma16(ah[kf], bl, acc);
        }
#pragma unroll
        for (int r = 0; r < 4; ++r)
            XQ[(size_t)(rowg0 + rh * 16 + quad * 4 + r) * PDIM + pt * 16 + m16] =
                f2bf(acc[r]);
    }
}

// ---------------- K3: fused attention — swapped QK + sigma-permuted keys, P in registers ----
// Wave w owns q-rows [w*16,w*16+16) for BOTH QK and PV (all 256 p). Swapped QK
// (mfma(A=Kt, B=qf)) gives lane (quad,m16): S[Kt-row quad*4+r][q=m16]. Kt rows are
// sigma-permuted at DMA time (sigma(r) = (r>>2)*8+(r&3), +4 for rows>=16), so the lane's
// 8 S-values are keys {quad*8+0..7} — EXACTLY the PV A-frag for q=m16. P never touches
// LDS: MFMA -> exp/relu -> bf16 pack -> MFMA, all in-register. Kt DMA/swizzle/read
// pattern byte-identical to R8. V-frags from L2-resident YVb (same lines across waves
// -> L1 broadcast), 4-frag groups double-buffered, first groups issued BEFORE the DMA.
__global__ __launch_bounds__(256, 2) void k_attn(const u16* __restrict__ XQ,
                                                 const u16* __restrict__ YK,
                                                 const u16* __restrict__ YVb,
                                                 u16* __restrict__ accE,
                                                 u16* __restrict__ accR,
                                                 float* __restrict__ lsum,
                                                 float* __restrict__ rsum,
                                                 int msPerSplit) {
    __shared__ u16 Kt[32 * 256];   // 32 keys x 256 d, XOR-swizzled chunks (16KB only)

    const int tid = threadIdx.x;
    const int wave = tid >> 6, lane = tid & 63;
    const int quad = lane >> 4, m16 = lane & 15;
    const int split = blockIdx.y;
    const int qbase = blockIdx.x * 64;
    const int key_begin = split * msPerSplit;
    const int iters = msPerSplit / BK;
    const int swz = m16 & 7;

    // Q frags for this wave's 16 q-rows (consumed as MFMA B operand — same lane content)
    s16x8 qf[8];
    const u16* qp = XQ + (size_t)(qbase + wave * 16 + m16) * DSIN;
#pragma unroll
    for (int kf = 0; kf < 8; ++kf)
        qf[kf] = *(const s16x8*)(qp + kf * 32 + quad * 8);

    f32x4 aE[16], aR[16];
#pragma unroll
    for (int t = 0; t < 16; ++t) {
        aE[t] = (f32x4){0.f, 0.f, 0.f, 0.f};
        aR[t] = (f32x4){0.f, 0.f, 0.f, 0.f};
    }
    float lacc = 0.f, racc = 0.f;

    // stage K tile: Kt row r <- YK key key0 + sigma(r); chunk XOR-swizzle same as R8
    auto stage = [&](int key0) {
#pragma unroll
        for (int c = 0; c < 4; ++c) {
            int l = (wave * 4 + c) * 64 + lane;   // phys chunk 0..1023
            int r = l >> 5;                        // Kt row 0..31
            int sg = ((r >> 2) & 3) * 8 + (r & 3) + ((r >> 4) << 2);  // sigma(r)
            int sc = (l & 31) ^ (r & 7);           // source chunk in row (swizzle)
            gload_lds16(YK + (size_t)(key0 + sg) * DSIN + sc * 8,
                        Kt + (size_t)(wave * 4 + c) * 512);
        }
    };
    stage(key_begin);

    for (int it = 0; it < iters; ++it) {
        const int key0 = key_begin + it * BK;
        __syncthreads();   // Kt(it) visible (vmcnt0 + barrier)

        // Swapped QK: s0 over Kt rows 0..15 (keys quad*8+0..3 per lane),
        //             s1 over rows 16..31 (keys quad*8+4..7)
        f32x4 s0 = (f32x4){0.f, 0.f, 0.f, 0.f};
        f32x4 s1 = (f32x4){0.f, 0.f, 0.f, 0.f};
        __builtin_amdgcn_s_setprio(1);
#pragma unroll
        for (int kf = 0; kf < 8; ++kf) {
            int pc = (kf * 4 + quad) ^ swz;        // (16+m16)&7 == m16&7
            s16x8 a0 = *(const s16x8*)(Kt + m16 * 256 + pc * 8);
            s16x8 a1 = *(const s16x8*)(Kt + (16 + m16) * 256 + pc * 8);
            s0 = mfma16(a0, qf[kf], s0);           // SWAPPED: A=K, B=Q
            s1 = mfma16(a1, qf[kf], s1);
        }
        __builtin_amdgcn_s_setprio(0);

        // exp/relu + in-register bf16 pack: pa/pb = P[q=m16][keys quad*8+0..7]
        float e0[4], e1[4], r0[4], r1[4];
#pragma unroll
        for (int r = 0; r < 4; ++r) {
            e0[r] = __expf(s0[r]);  r0[r] = fmaxf(s0[r], 0.f);
            e1[r] = __expf(s1[r]);  r1[r] = fmaxf(s1[r], 0.f);
            lacc += e0[r] + e1[r];
            racc += r0[r] + r1[r];
        }
        union { unsigned u[4]; s16x8 v; } pa, pb;
        pa.u[0] = ((unsigned)f2bf(e0[1]) << 16) | f2bf(e0[0]);
        pa.u[1] = ((unsigned)f2bf(e0[3]) << 16) | f2bf(e0[2]);
        pa.u[2] = ((unsigned)f2bf(e1[1]) << 16) | f2bf(e1[0]);
        pa.u[3] = ((unsigned)f2bf(e1[3]) << 16) | f2bf(e1[2]);
        pb.u[0] = ((unsigned)f2bf(r0[1]) << 16) | f2bf(r0[0]);
        pb.u[1] = ((unsigned)f2bf(r0[3]) << 16) | f2bf(r0[2]);
        pb.u[2] = ((unsigned)f2bf(r1[1]) << 16) | f2bf(r1[0]);
        pb.u[3] = ((unsigned)f2bf(r1[3]) << 16) | f2bf(r1[2]);

        __syncthreads();   // all waves' QK reads of Kt done -> Kt free to overwrite

        // V-frag groups (dbuf in regs); first two groups issued BEFORE the DMA so
        // their vmcnt waits never drain it (R8 ordering trick)
        const u16* vb = YVb + (size_t)((key0 >> 5) * PDIM) * 32;
        s16x8 vfa[4], vfb[4];
#pragma unroll
        for (int i = 0; i < 4; ++i)
            vfa[i] = *(const s16x8*)(vb + (size_t)(i * 16 + m16) * 32 + quad * 8);
#pragma unroll
        for (int i = 0; i < 4; ++i)
            vfb[i] = *(const s16x8*)(vb + (size_t)((4 + i) * 16 + m16) * 32 + quad * 8);

        if (it + 1 < iters) stage(key0 + BK);  // async prefetch of next K tile

        __builtin_amdgcn_s_setprio(1);
#pragma unroll
        for (int t = 0; t < 4; ++t) {
            aE[t] = mfma16(pa.v, vfa[t], aE[t]);
            aR[t] = mfma16(pb.v, vfa[t], aR[t]);
        }
#pragma unroll
        for (int i = 0; i < 4; ++i)
            vfa[i] = *(const s16x8*)(vb + (size_t)((8 + i) * 16 + m16) * 32 + quad * 8);
#pragma unroll
        for (int t = 0; t < 4; ++t) {
            aE[4 + t] = mfma16(pa.v, vfb[t], aE[4 + t]);
            aR[4 + t] = mfma16(pb.v, vfb[t], aR[4 + t]);
        }
#pragma unroll
        for (int i = 0; i < 4; ++i)
            vfb[i] = *(const s16x8*)(vb + (size_t)((12 + i) * 16 + m16) * 32 + quad * 8);
#pragma unroll
        for (int t = 0; t < 4; ++t) {
            aE[8 + t] = mfma16(pa.v, vfa[t], aE[8 + t]);
            aR[8 + t] = mfma16(pb.v, vfa[t], aR[8 + t]);
        }
#pragma unroll
        for (int t = 0; t < 4; ++t) {
            aE[12 + t] = mfma16(pa.v, vfb[t], aE[12 + t]);
            aR[12 + t] = mfma16(pb.v, vfb[t], aR[12 + t]);
        }
        __builtin_amdgcn_s_setprio(0);
    }

    // epilogue: bf16 partial O (rows quad*4+r of this wave's 16 q) and row sums
    size_t ob = ((size_t)split * N_Q + qbase) * PDIM;
#pragma unroll
    for (int t = 0; t < 16; ++t)
#pragma unroll
        for (int r = 0; r < 4; ++r) {
            size_t o = ob + (size_t)(wave * 16 + quad * 4 + r) * PDIM + t * 16 + m16;
            accE[o] = f2bf(aE[t][r]);
            accR[o] = f2bf(aR[t][r]);
        }
    // row sums: lane holds partial for q=m16 over its 8 keys; sum the 4 quads
    lacc += __shfl_xor(lacc, 16);
    lacc += __shfl_xor(lacc, 32);
    racc += __shfl_xor(racc, 16);
    racc += __shfl_xor(racc, 32);
    if (lane < 16) {
        int row = split * N_Q + qbase + wave * 16 + m16;
        lsum[row] = lacc;
        rsum[row] = racc;
    }
}

// ---------------- K4: combine splits + normalization (bf16 partials in) ----------------
__global__ void k_comb(const u16* __restrict__ accE, const u16* __restrict__ accR,
                       const float* __restrict__ lsum, const float* __restrict__ rsum,
                       float* __restrict__ out, int nsplit) {
    int row = blockIdx.x * 8 + (threadIdx.x >> 5);
    int col = (threadIdx.x & 31) * 8;
    size_t idx = (size_t)row * PDIM + col;
    const size_t NP = (size_t)N_Q * PDIM;
    float E[8] = {0.f, 0.f, 0.f, 0.f, 0.f, 0.f, 0.f, 0.f};
    float R[8] = {0.f, 0.f, 0.f, 0.f, 0.f, 0.f, 0.f, 0.f};
    float L = 0.f, Rs = 0.f;
    for (int s = 0; s < nsplit; ++s) {
        s16x8 e = *(const s16x8*)(accE + s * NP + idx);
        s16x8 r = *(const s16x8*)(accR + s * NP + idx);
#pragma unroll
        for (int j = 0; j < 8; ++j) {
            E[j] += bf2f((u16)e[j]);
            R[j] += bf2f((u16)r[j]);
        }
        L  += lsum[(size_t)s * N_Q + row];
        Rs += rsum[(size_t)s * N_Q + row];
    }
    float invL = 1.f / L, invD = 1.f / (1.f + 0.1f * Rs);
    float4 o0, o1;
    o0.x = (0.1f * R[0] + E[0] * invL) * invD;
    o0.y = (0.1f * R[1] + E[1] * invL) * invD;
    o0.z = (0.1f * R[2] + E[2] * invL) * invD;
    o0.w = (0.1f * R[3] + E[3] * invL) * invD;
    o1.x = (0.1f * R[4] + E[4] * invL) * invD;
    o1.y = (0.1f * R[5] + E[5] * invL) * invD;
    o1.z = (0.1f * R[6] + E[6] * invL) * invD;
    o1.w = (0.1f * R[7] + E[7] * invL) * invD;
    *(float4*)(out + idx) = o0;
    *(float4*)(out + idx + 4) = o1;
}

extern "C" void kernel_launch(void* const* d_in, const int* in_sizes, int n_in,
                              void* d_out, int out_size, void* d_ws, size_t ws_size,
                              hipStream_t stream) {
    const float* x  = (const float*)d_in[0];
    const float* y  = (const float*)d_in[1];
    const float* Wq = (const float*)d_in[2];
    const float* Wk = (const float*)d_in[3];
    const float* Wv = (const float*)d_in[4];
    float* out = (float*)d_out;

    char* ws = (char*)d_ws;
    size_t off = 0;
    auto take = [&](size_t bytes) -> char* {
        char* p = ws + off;
        off += (bytes + 255) & ~(size_t)255;
        return p;
    };
    u16* XQ  = (u16*)take((size_t)N_Q * PDIM * 2);
    u16* WtH = (u16*)take((size_t)PDIM * DSIN * 2);
    u16* WtL = (u16*)take((size_t)PDIM * DSIN * 2);
    u16* YK  = (u16*)take((size_t)MCTX * PDIM * 2);
    u16* YVb = (u16*)take((size_t)MCTX * PDIM * 2);

    size_t perSplit = (size_t)N_Q * PDIM * 2 * 2 + (size_t)N_Q * 4 * 2 + 1024;
    int nsplit = (ws_size >= off + 2 * perSplit + 4096) ? 2 : 1;

    u16*   accE = (u16*)take((size_t)nsplit * N_Q * PDIM * 2);
    u16*   accR = (u16*)take((size_t)nsplit * N_Q * PDIM * 2);
    float* lsum = (float*)take((size_t)nsplit * N_Q * 4);
    float* rsum = (float*)take((size_t)nsplit * N_Q * 4);

    hipLaunchKernelGGL(k_prep, dim3(PDIM + MCTX/32), dim3(256), 0, stream,
                       Wq, WtH, WtL, y, Wk, Wv, YK, YVb);
    hipLaunchKernelGGL(k_xq,   dim3(N_Q/32), dim3(256), 0, stream, x, WtH, WtL, XQ);
    hipLaunchKernelGGL(k_attn, dim3(N_Q/64, nsplit), dim3(256), 0, stream,
                       XQ, YK, YVb, accE, accR, lsum, rsum, MCTX / nsplit);
    hipLaunchKernelGGL(k_comb, dim3(N_Q/8), dim3(256), 0, stream,
                       accE, accR, lsum, rsum, out, nsplit);
}